// Round 1
// baseline (101.381 us; speedup 1.0000x reference)
//
#include <hip/hip_runtime.h>
#include <stdint.h>

typedef __bf16 bf16x8 __attribute__((ext_vector_type(8)));
typedef float f32x4 __attribute__((ext_vector_type(4)));

// ---------------------------------------------------------------------------
// async global->LDS 16B
__device__ __forceinline__ void gload16(const void* g, void* l) {
  __builtin_amdgcn_global_load_lds((const __attribute__((address_space(1))) void*)g,
                                   (__attribute__((address_space(3))) void*)l,
                                   16, 0, 0);
}

// ---------------------------------------------------------------------------
// Kernel 1: converts + transposes into bf16 working buffers
//  region 0: Xb[1792][512]   = bf16(concat(x_shot, x_query))
//  region 1: Wg1T[1024][512] : Wg1T[c][k] = c<512 ? Wg1[k][c] : Wg1[512+k][c-512]
//  region 2: Wg2T[512][512]  : Wg2T[n][k] = Wg2[k][n]
//  region 3: Wf1T[512][512]  : Wf1T[c][k] = Wf1[k][c]
__global__ void convert_all(const float* __restrict__ xs, const float* __restrict__ xq,
                            const float* __restrict__ Wg1, const float* __restrict__ Wg2,
                            const float* __restrict__ Wf1,
                            __bf16* __restrict__ Xb, __bf16* __restrict__ Wg1T,
                            __bf16* __restrict__ Wg2T, __bf16* __restrict__ Wf1T) {
  int e = blockIdx.x * 256 + threadIdx.x;
  if (e < 917504) {
    int row = e >> 9, k = e & 511;
    float v = (row < 768) ? xs[row * 512 + k] : xq[(row - 768) * 512 + k];
    Xb[e] = (__bf16)v;
  } else if (e < 1441792) {
    int e2 = e - 917504;
    int c = e2 >> 9, k = e2 & 511;
    float v = (c < 512) ? Wg1[k * 512 + c] : Wg1[(512 + k) * 512 + (c - 512)];
    Wg1T[e2] = (__bf16)v;
  } else if (e < 1703936) {
    int e2 = e - 1441792;
    int n = e2 >> 9, k = e2 & 511;
    Wg2T[e2] = (__bf16)Wg2[k * 512 + n];
  } else {
    int e2 = e - 1703936;
    int c = e2 >> 9, k = e2 & 511;
    Wf1T[e2] = (__bf16)Wf1[k * 512 + c];
  }
}

// ---------------------------------------------------------------------------
// Kernel 3: build padded pair-activation matrix Ab (36864 x 512, bf16)
//  rows [0,4096):   SS region, 128 groups (g=b*2+w) x 32 rows (30 valid)
//  rows [4096, ..): SQ region, 2048 groups (h=(b*16+q)*2+w) x 16 rows (12 valid)
//  row value = relu(U[rowU] + V[rowV] + bg1)   (UV[r][c]: c<512 -> U, c>=512 -> V)
__global__ void build_A(const float* __restrict__ UV, const float* __restrict__ bg1,
                        __bf16* __restrict__ Ab) {
  int gid = blockIdx.x * 256 + threadIdx.x;  // 36864*64 threads, 8 elems each
  int r = gid >> 6;
  int ke = (gid & 63) << 3;
  int rowU = 0, rowV = 0;
  bool pad = false;
  if (r < 4096) {
    int g = r >> 5, p = r & 31;
    if (p >= 30) pad = true;
    else {
      int i = p / 5, jj = p % 5;
      int j = jj + (jj >= i);
      int base = g * 6;
      rowU = base + j;
      rowV = base + i;
    }
  } else {
    int r2 = r - 4096;
    int h = r2 >> 4, p = r2 & 15;
    if (p >= 12) pad = true;
    else {
      int b = h >> 5, q = (h >> 1) & 15, wv = h & 1;
      int sbase = (b * 2 + wv) * 6;
      int qrow = 768 + b * 16 + q;
      if (p < 6) { rowU = qrow; rowV = sbase + p; }       // pair (i=p, j=query)
      else       { rowU = sbase + (p - 6); rowV = qrow; } // pair (i=query, j=p-6)
    }
  }
  float z[8];
  if (pad) {
#pragma unroll
    for (int e = 0; e < 8; e++) z[e] = 0.0f;
  } else {
    const float4* pu = (const float4*)(UV + (size_t)rowU * 1024 + ke);
    const float4* pv = (const float4*)(UV + (size_t)rowV * 1024 + 512 + ke);
    const float4* pb = (const float4*)(bg1 + ke);
    float4 u0 = pu[0], u1 = pu[1], v0 = pv[0], v1 = pv[1], b0 = pb[0], b1 = pb[1];
    z[0] = fmaxf(u0.x + v0.x + b0.x, 0.0f);
    z[1] = fmaxf(u0.y + v0.y + b0.y, 0.0f);
    z[2] = fmaxf(u0.z + v0.z + b0.z, 0.0f);
    z[3] = fmaxf(u0.w + v0.w + b0.w, 0.0f);
    z[4] = fmaxf(u1.x + v1.x + b1.x, 0.0f);
    z[5] = fmaxf(u1.y + v1.y + b1.y, 0.0f);
    z[6] = fmaxf(u1.z + v1.z + b1.z, 0.0f);
    z[7] = fmaxf(u1.w + v1.w + b1.w, 0.0f);
  }
  bf16x8 o;
#pragma unroll
  for (int e = 0; e < 8; e++) o[e] = (__bf16)z[e];
  *(bf16x8*)(Ab + (size_t)r * 512 + ke) = o;
}

// ---------------------------------------------------------------------------
// Generic 128x128-tile bf16 MFMA GEMM, C = A(MxK) * BT(NxK)^T, fp32 accum.
//  EPI 0: store raw fp32 C
//  EPI 1: store relu(C + bias[col]) fp32
//  EPI 2: relu(C + bias[col]) then per-group row reduction (WReN stage B):
//         row tiles < 32: 4 groups x 32 rows (30 valid) -> outSS
//         row tiles >=32: 8 groups x 16 rows (12 valid) -> outSQ
template <int EPI>
__global__ __launch_bounds__(256) void gemm128(const __bf16* __restrict__ A,
                                               const __bf16* __restrict__ BT,
                                               float* __restrict__ C,
                                               const float* __restrict__ bias,
                                               float* __restrict__ outSS,
                                               float* __restrict__ outSQ,
                                               int M, int N, int K) {
  constexpr int SMEM = (EPI == 2) ? (128 * 132 * 4) : 16384;
  __shared__ __align__(16) char smem[SMEM];
  __bf16* As = (__bf16*)smem;            // [128][32]
  __bf16* Bs = (__bf16*)(smem + 8192);   // [128][32]

  const int ntn = N >> 7;
  const int tm = blockIdx.x / ntn;
  const int tn = blockIdx.x % ntn;

  const int t = threadIdx.x;
  const int w = t >> 6, l = t & 63;
  const int wm = (w >> 1) << 6;  // wave tile row origin (0/64)
  const int wn = (w & 1) << 6;   // wave tile col origin (0/64)
  const int lr = l & 15, lg = l >> 4;

  // staging addresses: thread t covers A row t/4 (and +64), k-chunk (t%4)*8
  const int arow0 = t >> 2;
  const int kch = (t & 3) * 8;
  const __bf16* Ag  = A + (size_t)(tm * 128 + arow0) * K + kch;
  const __bf16* Ag2 = Ag + (size_t)64 * K;
  const __bf16* Bg  = BT + (size_t)(tn * 128 + arow0) * K + kch;
  const __bf16* Bg2 = Bg + (size_t)64 * K;
  char* lA  = smem + t * 16;
  char* lA2 = smem + 4096 + t * 16;
  char* lB  = smem + 8192 + t * 16;
  char* lB2 = smem + 8192 + 4096 + t * 16;

  f32x4 acc[4][4];
#pragma unroll
  for (int m = 0; m < 4; m++)
#pragma unroll
    for (int n = 0; n < 4; n++) acc[m][n] = (f32x4){0.f, 0.f, 0.f, 0.f};

  for (int k0 = 0; k0 < K; k0 += 32) {
    gload16(Ag + k0, lA);
    gload16(Ag2 + k0, lA2);
    gload16(Bg + k0, lB);
    gload16(Bg2 + k0, lB2);
    asm volatile("s_waitcnt vmcnt(0)" ::: "memory");
    __syncthreads();

    bf16x8 fa[4], fb[4];
#pragma unroll
    for (int m = 0; m < 4; m++)
      fa[m] = *(const bf16x8*)(As + (wm + m * 16 + lr) * 32 + lg * 8);
#pragma unroll
    for (int n = 0; n < 4; n++)
      fb[n] = *(const bf16x8*)(Bs + (wn + n * 16 + lr) * 32 + lg * 8);
#pragma unroll
    for (int m = 0; m < 4; m++)
#pragma unroll
      for (int n = 0; n < 4; n++)
        acc[m][n] = __builtin_amdgcn_mfma_f32_16x16x32_bf16(fa[m], fb[n], acc[m][n], 0, 0, 0);
    __syncthreads();
  }

  if (EPI == 0 || EPI == 1) {
#pragma unroll
    for (int m = 0; m < 4; m++)
#pragma unroll
      for (int n = 0; n < 4; n++) {
        int col = tn * 128 + wn + n * 16 + lr;
#pragma unroll
        for (int reg = 0; reg < 4; reg++) {
          int row = tm * 128 + wm + m * 16 + lg * 4 + reg;
          float v = acc[m][n][reg];
          if (EPI == 1) v = fmaxf(v + bias[col], 0.0f);
          C[(size_t)row * N + col] = v;
        }
      }
  } else {
    // EPI 2: relu+bias into LDS tile [128][132], then group-row reduce
    float* tile = (float*)smem;
#pragma unroll
    for (int m = 0; m < 4; m++)
#pragma unroll
      for (int n = 0; n < 4; n++) {
        int c = wn + n * 16 + lr;
        float bv = bias[tn * 128 + c];
#pragma unroll
        for (int reg = 0; reg < 4; reg++) {
          int r = wm + m * 16 + lg * 4 + reg;
          tile[r * 132 + c] = fmaxf(acc[m][n][reg] + bv, 0.0f);
        }
      }
    __syncthreads();
    const bool ssr = (tm < 32);
    const int G = ssr ? 4 : 8;
    const int rpg = ssr ? 32 : 16;
    const int valid = ssr ? 30 : 12;
    const int nout = G * 128;
    for (int o = t; o < nout; o += 256) {
      int g = o >> 7, c = o & 127;
      float s = 0.0f;
      for (int p = 0; p < valid; p++) s += tile[(g * rpg + p) * 132 + c];
      if (ssr)
        outSS[(size_t)(tm * 4 + g) * 512 + tn * 128 + c] = s;
      else
        outSQ[(size_t)((tm - 32) * 8 + g) * 512 + tn * 128 + c] = s;
    }
  }
}

// ---------------------------------------------------------------------------
// Kernel 5: Sb[r][k] = bf16(SS[(r>>5)*2 + (r&1)][k] + SQ[r][k])
__global__ void combine_s(const float* __restrict__ SS, const float* __restrict__ SQ,
                          __bf16* __restrict__ Sb) {
  int gid = blockIdx.x * 256 + threadIdx.x;  // 2048*64 threads, 8 elems each
  int r = gid >> 6;
  int k = (gid & 63) << 3;
  const float4* a = (const float4*)(SS + (size_t)((r >> 5) * 2 + (r & 1)) * 512 + k);
  const float4* b = (const float4*)(SQ + (size_t)r * 512 + k);
  float4 a0 = a[0], a1 = a[1], b0 = b[0], b1 = b[1];
  bf16x8 o;
  o[0] = (__bf16)(a0.x + b0.x);
  o[1] = (__bf16)(a0.y + b0.y);
  o[2] = (__bf16)(a0.z + b0.z);
  o[3] = (__bf16)(a0.w + b0.w);
  o[4] = (__bf16)(a1.x + b1.x);
  o[5] = (__bf16)(a1.y + b1.y);
  o[6] = (__bf16)(a1.z + b1.z);
  o[7] = (__bf16)(a1.w + b1.w);
  *(bf16x8*)(Sb + (size_t)r * 512 + k) = o;
}

// ---------------------------------------------------------------------------
// Kernel 7: logit[r] = dot(h[r], Wf2) + bf2   (one wave per row)
__global__ void final_dot(const float* __restrict__ h, const float* __restrict__ Wf2,
                          const float* __restrict__ bf2, float* __restrict__ out) {
  int row = blockIdx.x * 4 + (threadIdx.x >> 6);
  int l = threadIdx.x & 63;
  const float4* hp = (const float4*)(h + (size_t)row * 512);
  const float4* wp = (const float4*)Wf2;
  float s = 0.0f;
#pragma unroll
  for (int i = 0; i < 2; i++) {
    float4 a = hp[l + 64 * i];
    float4 b = wp[l + 64 * i];
    s += a.x * b.x + a.y * b.y + a.z * b.z + a.w * b.w;
  }
#pragma unroll
  for (int off = 32; off; off >>= 1) s += __shfl_down(s, off, 64);
  if (l == 0) out[row] = s + bf2[0];
}

// ---------------------------------------------------------------------------
extern "C" void kernel_launch(void* const* d_in, const int* in_sizes, int n_in,
                              void* d_out, int out_size, void* d_ws, size_t ws_size,
                              hipStream_t stream) {
  const float* xs  = (const float*)d_in[0];
  const float* xq  = (const float*)d_in[1];
  const float* Wg1 = (const float*)d_in[2];
  const float* bg1 = (const float*)d_in[3];
  const float* Wg2 = (const float*)d_in[4];
  const float* bg2 = (const float*)d_in[5];
  const float* Wf1 = (const float*)d_in[6];
  const float* bf1 = (const float*)d_in[7];
  const float* Wf2 = (const float*)d_in[8];
  const float* bf2 = (const float*)d_in[9];
  float* out = (float*)d_out;

  char* ws = (char*)d_ws;
  __bf16* Xb   = (__bf16*)(ws);             // 1792*512*2   = 1,835,008
  __bf16* Wg1T = (__bf16*)(ws + 1835008);   // 1024*512*2   = 1,048,576
  __bf16* Wg2T = (__bf16*)(ws + 2883584);   // 512*512*2    =   524,288
  __bf16* Wf1T = (__bf16*)(ws + 3407872);   // 512*512*2    =   524,288
  float*  UV   = (float*)(ws + 3932160);    // 1792*1024*4  = 7,340,032
  __bf16* Ab   = (__bf16*)(ws + 11272192);  // 36864*512*2  = 37,748,736
  float*  SSs  = (float*)(ws + 49020928);   // 128*512*4    =   262,144
  float*  SQs  = (float*)(ws + 49283072);   // 2048*512*4   = 4,194,304
  __bf16* Sb   = (__bf16*)(ws + 53477376);  // 2048*512*2   = 2,097,152
  float*  Hf   = (float*)(ws + 55574528);   // 2048*512*4   = 4,194,304
  // total ~59.8 MB of d_ws

  // 1. converts / transposes
  convert_all<<<7680, 256, 0, stream>>>(xs, xq, Wg1, Wg2, Wf1, Xb, Wg1T, Wg2T, Wf1T);
  // 2. layer-1 GEMM: UV[1792][1024] = Xb @ [Wg1_top | Wg1_bot]
  gemm128<0><<<112, 256, 0, stream>>>(Xb, Wg1T, UV, nullptr, nullptr, nullptr, 1792, 1024, 512);
  // 3. build pair activations
  build_A<<<9216, 256, 0, stream>>>(UV, bg1, Ab);
  // 4. layer-2 GEMM + relu+bias + group reduction
  gemm128<2><<<1152, 256, 0, stream>>>(Ab, Wg2T, nullptr, bg2, SSs, SQs, 36864, 512, 512);
  // 5. S = SS + SQ -> bf16
  combine_s<<<512, 256, 0, stream>>>(SSs, SQs, Sb);
  // 6. layer-3 GEMM: H = relu(S @ Wf1 + bf1)
  gemm128<1><<<64, 256, 0, stream>>>(Sb, Wf1T, Hf, bf1, nullptr, nullptr, 2048, 512, 512);
  // 7. logits
  final_dot<<<512, 256, 0, stream>>>(Hf, Wf2, bf2, out);
}

// Round 2
// 90.048 us; speedup vs baseline: 1.1259x; 1.1259x over previous
//
#include <hip/hip_runtime.h>
#include <stdint.h>

typedef __bf16 bf16x8 __attribute__((ext_vector_type(8)));
typedef float f32x4 __attribute__((ext_vector_type(4)));

// ---------------------------------------------------------------------------
// async global->LDS 16B
__device__ __forceinline__ void gload16(const void* g, void* l) {
  __builtin_amdgcn_global_load_lds((const __attribute__((address_space(1))) void*)g,
                                   (__attribute__((address_space(3))) void*)l,
                                   16, 0, 0);
}

// ---------------------------------------------------------------------------
// Kernel 1: converts + transposes into bf16 working buffers
__global__ void convert_all(const float* __restrict__ xs, const float* __restrict__ xq,
                            const float* __restrict__ Wg1, const float* __restrict__ Wg2,
                            const float* __restrict__ Wf1,
                            __bf16* __restrict__ Xb, __bf16* __restrict__ Wg1T,
                            __bf16* __restrict__ Wg2T, __bf16* __restrict__ Wf1T) {
  int e = blockIdx.x * 256 + threadIdx.x;
  if (e < 917504) {
    int row = e >> 9, k = e & 511;
    float v = (row < 768) ? xs[row * 512 + k] : xq[(row - 768) * 512 + k];
    Xb[e] = (__bf16)v;
  } else if (e < 1441792) {
    int e2 = e - 917504;
    int c = e2 >> 9, k = e2 & 511;
    float v = (c < 512) ? Wg1[k * 512 + c] : Wg1[(512 + k) * 512 + (c - 512)];
    Wg1T[e2] = (__bf16)v;
  } else if (e < 1703936) {
    int e2 = e - 1441792;
    int n = e2 >> 9, k = e2 & 511;
    Wg2T[e2] = (__bf16)Wg2[k * 512 + n];
  } else {
    int e2 = e - 1703936;
    int c = e2 >> 9, k = e2 & 511;
    Wf1T[e2] = (__bf16)Wf1[k * 512 + c];
  }
}

// ---------------------------------------------------------------------------
// Kernel 3: build padded pair-activation matrix Ab (36864 x 512, bf16)
__global__ void build_A(const float* __restrict__ UV, const float* __restrict__ bg1,
                        __bf16* __restrict__ Ab) {
  int gid = blockIdx.x * 256 + threadIdx.x;  // 36864*64 threads, 8 elems each
  int r = gid >> 6;
  int ke = (gid & 63) << 3;
  int rowU = 0, rowV = 0;
  bool pad = false;
  if (r < 4096) {
    int g = r >> 5, p = r & 31;
    if (p >= 30) pad = true;
    else {
      int i = p / 5, jj = p % 5;
      int j = jj + (jj >= i);
      int base = g * 6;
      rowU = base + j;
      rowV = base + i;
    }
  } else {
    int r2 = r - 4096;
    int h = r2 >> 4, p = r2 & 15;
    if (p >= 12) pad = true;
    else {
      int b = h >> 5, q = (h >> 1) & 15, wv = h & 1;
      int sbase = (b * 2 + wv) * 6;
      int qrow = 768 + b * 16 + q;
      if (p < 6) { rowU = qrow; rowV = sbase + p; }
      else       { rowU = sbase + (p - 6); rowV = qrow; }
    }
  }
  float z[8];
  if (pad) {
#pragma unroll
    for (int e = 0; e < 8; e++) z[e] = 0.0f;
  } else {
    const float4* pu = (const float4*)(UV + (size_t)rowU * 1024 + ke);
    const float4* pv = (const float4*)(UV + (size_t)rowV * 1024 + 512 + ke);
    const float4* pb = (const float4*)(bg1 + ke);
    float4 u0 = pu[0], u1 = pu[1], v0 = pv[0], v1 = pv[1], b0 = pb[0], b1 = pb[1];
    z[0] = fmaxf(u0.x + v0.x + b0.x, 0.0f);
    z[1] = fmaxf(u0.y + v0.y + b0.y, 0.0f);
    z[2] = fmaxf(u0.z + v0.z + b0.z, 0.0f);
    z[3] = fmaxf(u0.w + v0.w + b0.w, 0.0f);
    z[4] = fmaxf(u1.x + v1.x + b1.x, 0.0f);
    z[5] = fmaxf(u1.y + v1.y + b1.y, 0.0f);
    z[6] = fmaxf(u1.z + v1.z + b1.z, 0.0f);
    z[7] = fmaxf(u1.w + v1.w + b1.w, 0.0f);
  }
  bf16x8 o;
#pragma unroll
  for (int e = 0; e < 8; e++) o[e] = (__bf16)z[e];
  *(bf16x8*)(Ab + (size_t)r * 512 + ke) = o;
}

// ---------------------------------------------------------------------------
// Generic 128x128-tile bf16 MFMA GEMM, C = A(MxK) * BT(NxK)^T, fp32 accum.
// LDS chunk-swizzled (chunk ^= (row>>2)&3) for conflict-free ds_read_b128.
//  EPI 0: store raw fp32 C
//  EPI 1: store relu(C + bias[col]) fp32
//  EPI 2: relu(C + bias[col]) then register-space per-group row reduction:
//         row tiles < 32: 4 groups x 32 rows (30 valid) -> outSS
//         row tiles >=32: 8 groups x 16 rows (12 valid) -> outSQ
template <int EPI>
__global__ __launch_bounds__(256) void gemm128(const __bf16* __restrict__ A,
                                               const __bf16* __restrict__ BT,
                                               float* __restrict__ C,
                                               const float* __restrict__ bias,
                                               float* __restrict__ outSS,
                                               float* __restrict__ outSQ,
                                               int M, int N, int K) {
  __shared__ __align__(16) char smem[16384];
  __bf16* As = (__bf16*)smem;            // [128][32], chunk-swizzled
  __bf16* Bs = (__bf16*)(smem + 8192);   // [128][32], chunk-swizzled

  // XCD-chunked bijective swizzle (grids here are all multiples of 8)
  int bid = blockIdx.x;
  {
    int nwg = gridDim.x;
    if ((nwg & 7) == 0) { int q = nwg >> 3; bid = (bid & 7) * q + (bid >> 3); }
  }
  const int ntn = N >> 7;
  const int tm = bid / ntn;
  const int tn = bid % ntn;

  const int t = threadIdx.x;
  const int w = t >> 6, l = t & 63;
  const int wm = (w >> 1) << 6;  // wave tile row origin (0/64)
  const int wn = (w & 1) << 6;   // wave tile col origin (0/64)
  const int lr = l & 15, lg = l >> 4;

  // staging: thread t owns LDS row t>>2 (and +64), LDS chunk t&3.
  // Source k-chunk is inverse-swizzled: srcchunk = (t&3) ^ ((row>>2)&3), row=t>>2.
  const int arow0 = t >> 2;
  const int kch = (((t & 3) ^ ((t >> 4) & 3)) * 8);
  const __bf16* Ag  = A + (size_t)(tm * 128 + arow0) * K + kch;
  const __bf16* Ag2 = Ag + (size_t)64 * K;
  const __bf16* Bg  = BT + (size_t)(tn * 128 + arow0) * K + kch;
  const __bf16* Bg2 = Bg + (size_t)64 * K;
  char* lA  = smem + t * 16;
  char* lA2 = smem + 4096 + t * 16;
  char* lB  = smem + 8192 + t * 16;
  char* lB2 = smem + 8192 + 4096 + t * 16;

  f32x4 acc[4][4];
#pragma unroll
  for (int m = 0; m < 4; m++)
#pragma unroll
    for (int n = 0; n < 4; n++) acc[m][n] = (f32x4){0.f, 0.f, 0.f, 0.f};

  // read-side swizzled chunk: lg ^ (lr>>2)  (since wm, m*16 are multiples of 16)
  const int rchunk = (lg ^ (lr >> 2)) * 8;

  for (int k0 = 0; k0 < K; k0 += 32) {
    gload16(Ag + k0, lA);
    gload16(Ag2 + k0, lA2);
    gload16(Bg + k0, lB);
    gload16(Bg2 + k0, lB2);
    asm volatile("s_waitcnt vmcnt(0)" ::: "memory");
    __syncthreads();

    bf16x8 fa[4], fb[4];
#pragma unroll
    for (int m = 0; m < 4; m++)
      fa[m] = *(const bf16x8*)(As + (wm + m * 16 + lr) * 32 + rchunk);
#pragma unroll
    for (int n = 0; n < 4; n++)
      fb[n] = *(const bf16x8*)(Bs + (wn + n * 16 + lr) * 32 + rchunk);
#pragma unroll
    for (int m = 0; m < 4; m++)
#pragma unroll
      for (int n = 0; n < 4; n++)
        acc[m][n] = __builtin_amdgcn_mfma_f32_16x16x32_bf16(fa[m], fb[n], acc[m][n], 0, 0, 0);
    __syncthreads();
  }

  if (EPI == 0 || EPI == 1) {
#pragma unroll
    for (int m = 0; m < 4; m++)
#pragma unroll
      for (int n = 0; n < 4; n++) {
        int col = tn * 128 + wn + n * 16 + lr;
#pragma unroll
        for (int reg = 0; reg < 4; reg++) {
          int row = tm * 128 + wm + m * 16 + lg * 4 + reg;
          float v = acc[m][n][reg];
          if (EPI == 1) v = fmaxf(v + bias[col], 0.0f);
          C[(size_t)row * N + col] = v;
        }
      }
  } else {
    // EPI 2: relu+bias in-register, then group reduction via shfl.
    // Row of acc[m][n][reg] = wm + m*16 + lg*4 + reg.
    if (tm < 32) {
      // SS: groups of 32 rows, rows 30,31 are pad. Pad rows sit in odd-m frags
      // at lg*4+reg >= 14.
#pragma unroll
      for (int pair = 0; pair < 2; pair++) {
#pragma unroll
        for (int n = 0; n < 4; n++) {
          int col = tn * 128 + wn + n * 16 + lr;
          float bv = bias[col];
          float s = 0.0f;
#pragma unroll
          for (int mh = 0; mh < 2; mh++) {
            int m = pair * 2 + mh;
#pragma unroll
            for (int reg = 0; reg < 4; reg++) {
              bool ok = (mh == 0) || (lg * 4 + reg < 14);
              float v = fmaxf(acc[m][n][reg] + bv, 0.0f);
              s += ok ? v : 0.0f;
            }
          }
          s += __shfl_xor(s, 16);
          s += __shfl_xor(s, 32);
          if (l < 16) {
            int g = (wm >> 5) + pair;  // 0..3
            outSS[(size_t)(tm * 4 + g) * 512 + col] = s;
          }
        }
      }
    } else {
      // SQ: groups of 16 rows, rows 12..15 pad -> lg==3 invalid.
#pragma unroll
      for (int m = 0; m < 4; m++) {
#pragma unroll
        for (int n = 0; n < 4; n++) {
          int col = tn * 128 + wn + n * 16 + lr;
          float bv = bias[col];
          float s = 0.0f;
#pragma unroll
          for (int reg = 0; reg < 4; reg++) {
            float v = fmaxf(acc[m][n][reg] + bv, 0.0f);
            s += (lg < 3) ? v : 0.0f;
          }
          s += __shfl_xor(s, 16);
          s += __shfl_xor(s, 32);
          if (l < 16) {
            int h = (tm - 32) * 8 + (wm >> 4) + m;  // global SQ group
            outSQ[(size_t)h * 512 + col] = s;
          }
        }
      }
    }
  }
}

// ---------------------------------------------------------------------------
// Kernel 5: Sb[r][k] = bf16(SS[(r>>5)*2 + (r&1)][k] + SQ[r][k])
__global__ void combine_s(const float* __restrict__ SS, const float* __restrict__ SQ,
                          __bf16* __restrict__ Sb) {
  int gid = blockIdx.x * 256 + threadIdx.x;
  int r = gid >> 6;
  int k = (gid & 63) << 3;
  const float4* a = (const float4*)(SS + (size_t)((r >> 5) * 2 + (r & 1)) * 512 + k);
  const float4* b = (const float4*)(SQ + (size_t)r * 512 + k);
  float4 a0 = a[0], a1 = a[1], b0 = b[0], b1 = b[1];
  bf16x8 o;
  o[0] = (__bf16)(a0.x + b0.x);
  o[1] = (__bf16)(a0.y + b0.y);
  o[2] = (__bf16)(a0.z + b0.z);
  o[3] = (__bf16)(a0.w + b0.w);
  o[4] = (__bf16)(a1.x + b1.x);
  o[5] = (__bf16)(a1.y + b1.y);
  o[6] = (__bf16)(a1.z + b1.z);
  o[7] = (__bf16)(a1.w + b1.w);
  *(bf16x8*)(Sb + (size_t)r * 512 + k) = o;
}

// ---------------------------------------------------------------------------
// Kernel 7: logit[r] = dot(h[r], Wf2) + bf2   (one wave per row)
__global__ void final_dot(const float* __restrict__ h, const float* __restrict__ Wf2,
                          const float* __restrict__ bf2, float* __restrict__ out) {
  int row = blockIdx.x * 4 + (threadIdx.x >> 6);
  int l = threadIdx.x & 63;
  const float4* hp = (const float4*)(h + (size_t)row * 512);
  const float4* wp = (const float4*)Wf2;
  float s = 0.0f;
#pragma unroll
  for (int i = 0; i < 2; i++) {
    float4 a = hp[l + 64 * i];
    float4 b = wp[l + 64 * i];
    s += a.x * b.x + a.y * b.y + a.z * b.z + a.w * b.w;
  }
#pragma unroll
  for (int off = 32; off; off >>= 1) s += __shfl_down(s, off, 64);
  if (l == 0) out[row] = s + bf2[0];
}

// ---------------------------------------------------------------------------
extern "C" void kernel_launch(void* const* d_in, const int* in_sizes, int n_in,
                              void* d_out, int out_size, void* d_ws, size_t ws_size,
                              hipStream_t stream) {
  const float* xs  = (const float*)d_in[0];
  const float* xq  = (const float*)d_in[1];
  const float* Wg1 = (const float*)d_in[2];
  const float* bg1 = (const float*)d_in[3];
  const float* Wg2 = (const float*)d_in[4];
  const float* bg2 = (const float*)d_in[5];
  const float* Wf1 = (const float*)d_in[6];
  const float* bf1 = (const float*)d_in[7];
  const float* Wf2 = (const float*)d_in[8];
  const float* bf2 = (const float*)d_in[9];
  float* out = (float*)d_out;

  char* ws = (char*)d_ws;
  __bf16* Xb   = (__bf16*)(ws);             // 1792*512*2   = 1,835,008
  __bf16* Wg1T = (__bf16*)(ws + 1835008);   // 1024*512*2   = 1,048,576
  __bf16* Wg2T = (__bf16*)(ws + 2883584);   // 512*512*2    =   524,288
  __bf16* Wf1T = (__bf16*)(ws + 3407872);   // 512*512*2    =   524,288
  float*  UV   = (float*)(ws + 3932160);    // 1792*1024*4  = 7,340,032
  __bf16* Ab   = (__bf16*)(ws + 11272192);  // 36864*512*2  = 37,748,736
  float*  SSs  = (float*)(ws + 49020928);   // 128*512*4    =   262,144
  float*  SQs  = (float*)(ws + 49283072);   // 2048*512*4   = 4,194,304
  __bf16* Sb   = (__bf16*)(ws + 53477376);  // 2048*512*2   = 2,097,152
  float*  Hf   = (float*)(ws + 55574528);   // 2048*512*4   = 4,194,304

  convert_all<<<7680, 256, 0, stream>>>(xs, xq, Wg1, Wg2, Wf1, Xb, Wg1T, Wg2T, Wf1T);
  gemm128<0><<<112, 256, 0, stream>>>(Xb, Wg1T, UV, nullptr, nullptr, nullptr, 1792, 1024, 512);
  build_A<<<9216, 256, 0, stream>>>(UV, bg1, Ab);
  gemm128<2><<<1152, 256, 0, stream>>>(Ab, Wg2T, nullptr, bg2, SSs, SQs, 36864, 512, 512);
  combine_s<<<512, 256, 0, stream>>>(SSs, SQs, Sb);
  gemm128<1><<<64, 256, 0, stream>>>(Sb, Wf1T, Hf, bf1, nullptr, nullptr, 2048, 512, 512);
  final_dot<<<512, 256, 0, stream>>>(Hf, Wf2, bf2, out);
}